// Round 8
// baseline (860.412 us; speedup 1.0000x reference)
//
#include <hip/hip_runtime.h>

#define S      4096
#define D      512
#define KWIN   3
#define SP     (S + 2)          // zero-padded rows: g = s + tap, g in [0, S+1]
#define MAXOUT 16384
#define EPSLN  1e-5f
#define NIT    16               // i-tiles per tap (512/32)
#define NKT    48               // total K tiles of 32 (1536/32)
#define KSPLIT 4
#define KQ     (NKT / KSPLIT)   // 12 K32-stages per block
#define NBLK   512              // persistent grid: exactly 2 blocks/CU

typedef __attribute__((ext_vector_type(8)))  short short8;
typedef __attribute__((ext_vector_type(16))) float floatx16;

__device__ inline ushort f2bf(float x) {
  union { float f; unsigned u; } v; v.f = x;
  unsigned r = v.u + 0x7fffu + ((v.u >> 16) & 1u);
  return (ushort)(r >> 16);
}
__device__ inline float bf2f(ushort h) {
  union { float f; unsigned u; } v; v.u = ((unsigned)h) << 16;
  return v.f;
}

__device__ inline void gload16(const void* g, void* l) {
  __builtin_amdgcn_global_load_lds((const __attribute__((address_space(1))) void*)g,
                                   (__attribute__((address_space(3))) void*)l,
                                   16, 0, 0);
}

__device__ inline void load8(const float* p, int lane, float o[8]) {
  const float4 a = ((const float4*)p)[2 * lane];
  const float4 b = ((const float4*)p)[2 * lane + 1];
  o[0] = a.x; o[1] = a.y; o[2] = a.z; o[3] = a.w;
  o[4] = b.x; o[5] = b.y; o[6] = b.z; o[7] = b.w;
}

// ---------------------------------------------------------------------------
// Software grid barrier: device-scope atomic counter per phase, zeroed by the
// preceding zero_bar kernel. Grid is exactly co-resident (512 blocks at
// 2 blocks/CU x 256 CUs) so the spin cannot deadlock.
// ---------------------------------------------------------------------------
__device__ inline void gridbar(int* __restrict__ bar, int phase) {
  __syncthreads();
  __threadfence();                               // release our writes (agent)
  if (threadIdx.x == 0) {
    __hip_atomic_fetch_add(&bar[phase], 1, __ATOMIC_ACQ_REL, __HIP_MEMORY_SCOPE_AGENT);
    while (__hip_atomic_load(&bar[phase], __ATOMIC_RELAXED, __HIP_MEMORY_SCOPE_AGENT) < NBLK)
      __builtin_amdgcn_s_sleep(2);
  }
  __syncthreads();
  __threadfence();                               // acquire others' writes
}

__global__ __launch_bounds__(64) void zero_bar_kernel(int* __restrict__ bar) {
  if (threadIdx.x < 16) bar[threadIdx.x] = 0;
}

// ---------------------------------------------------------------------------
// Weight pack helper (identical math to R7).
// ---------------------------------------------------------------------------
__device__ inline void wpack8(const float* __restrict__ w, ushort* __restrict__ bh,
                              ushort* __restrict__ bl, int q) {
  const int kk0 = (q & 3) * 8;
  const int o   = (q >> 2) & 511;
  const int it  = (q >> 11) & 15;
  const int k   = q >> 15;             // 0..2
  short8 h8, l8;
#pragma unroll
  for (int j = 0; j < 8; ++j) {
    const float v = w[o * (D * KWIN) + (it * 32 + kk0 + j) * KWIN + k];
    const ushort hi = f2bf(v);
    h8[j] = (short)hi;
    l8[j] = (short)f2bf(v - bf2f(hi));
  }
  *(short8*)(bh + (size_t)q * 8) = h8;
  *(short8*)(bl + (size_t)q * 8) = l8;
}

// ---------------------------------------------------------------------------
// GEMM phase (identical numerics to R7: 32x32x16 MFMA, hi/lo hh+hl+lh,
// 128x128 block tile, split-K=4, dbuf LDS, (r>>1)&3 XOR bank swizzle,
// product-outermost MFMA issue).  bid -> (x = bid&31, y = (bid>>5)&3,
// z = bid>>7); 512 blocks cover the full grid.
// ---------------------------------------------------------------------------
__device__ void gemm_phase(const ushort* __restrict__ Ah, const ushort* __restrict__ Al,
                           const ushort* __restrict__ Bh, const ushort* __restrict__ Bl,
                           float* __restrict__ Cpart,
                           ushort (*smem)[4][4096], int bid, int tid) {
  const int wave = tid >> 6;
  const int lane = tid & 63;
  const int row0 = (bid & 31) * 128;
  const int col0 = ((bid >> 5) & 3) * 128;
  const int zz   = bid >> 7;
  const int ktb  = zz * KQ;
  const int wm0  = (wave >> 1) * 64;
  const int wn0  = (wave & 1) * 64;
  const int ln31 = lane & 31;
  const int half = lane >> 5;

  floatx16 acc[2][2] = {};

  auto stage = [&](int stg, int db) {
    const int kt    = ktb + stg;
    const int tap   = kt >> 4;
    const int itile = kt & 15;
    const ushort* gb;
    if (wave == 0)      gb = Ah + ((size_t)itile * SP + row0 + tap) * 32;
    else if (wave == 1) gb = Al + ((size_t)itile * SP + row0 + tap) * 32;
    else if (wave == 2) gb = Bh + ((size_t)kt * D + col0) * 32;
    else                gb = Bl + ((size_t)kt * D + col0) * 32;
    ushort* lb = &smem[db][wave][0];
#pragma unroll
    for (int seg = 0; seg < 8; ++seg) {
      const int r = seg * 16 + (lane >> 2);
      const int c = (lane & 3) ^ ((r >> 1) & 3);
      gload16(gb + (size_t)r * 32 + c * 8, lb + seg * 512);
    }
  };

  stage(0, 0);

  for (int p = 0; p < KQ; ++p) {
    const int db = p & 1;
    __syncthreads();
    if (p + 1 < KQ) stage(p + 1, db ^ 1);

    short8 ah[2][2], al2[2][2], bh[2][2], bl2[2][2];
#pragma unroll
    for (int sub = 0; sub < 2; ++sub) {
      const int cc = sub * 2 + half;
#pragma unroll
      for (int mf = 0; mf < 2; ++mf) {
        const int r   = wm0 + mf * 32 + ln31;
        const int cs  = cc ^ ((r >> 1) & 3);
        const int off = r * 32 + cs * 8;
        ah[sub][mf]  = *(const short8*)&smem[db][0][off];
        al2[sub][mf] = *(const short8*)&smem[db][1][off];
      }
#pragma unroll
      for (int nf = 0; nf < 2; ++nf) {
        const int r   = wn0 + nf * 32 + ln31;
        const int cs  = cc ^ ((r >> 1) & 3);
        const int off = r * 32 + cs * 8;
        bh[sub][nf]  = *(const short8*)&smem[db][2][off];
        bl2[sub][nf] = *(const short8*)&smem[db][3][off];
      }
    }

#pragma unroll
    for (int sub = 0; sub < 2; ++sub) {
#pragma unroll
      for (int mf = 0; mf < 2; ++mf)
#pragma unroll
        for (int nf = 0; nf < 2; ++nf)
          acc[mf][nf] = __builtin_amdgcn_mfma_f32_32x32x16_bf16(
              ah[sub][mf], bh[sub][nf], acc[mf][nf], 0, 0, 0);
#pragma unroll
      for (int mf = 0; mf < 2; ++mf)
#pragma unroll
        for (int nf = 0; nf < 2; ++nf)
          acc[mf][nf] = __builtin_amdgcn_mfma_f32_32x32x16_bf16(
              ah[sub][mf], bl2[sub][nf], acc[mf][nf], 0, 0, 0);
#pragma unroll
      for (int mf = 0; mf < 2; ++mf)
#pragma unroll
        for (int nf = 0; nf < 2; ++nf)
          acc[mf][nf] = __builtin_amdgcn_mfma_f32_32x32x16_bf16(
              al2[sub][mf], bh[sub][nf], acc[mf][nf], 0, 0, 0);
    }
  }
  __syncthreads();   // LDS reads done before next phase reuses smem

  float* C = Cpart + (size_t)zz * S * D;
#pragma unroll
  for (int mf = 0; mf < 2; ++mf)
#pragma unroll
    for (int nf = 0; nf < 2; ++nf) {
      const int col = col0 + wn0 + nf * 32 + ln31;
#pragma unroll
      for (int reg = 0; reg < 16; ++reg) {
        const int row = row0 + wm0 + mf * 32 + (reg & 3) + 8 * (reg >> 2) + 4 * half;
        C[(size_t)row * D + col] = acc[mf][nf][reg];
      }
    }
}

// ---------------------------------------------------------------------------
// LN core: (sum of 4 partials + bias) -> LN stats. Returns normalized v[8],
// rs, and loads gamma/beta. Fixed reduction order -> deterministic.
// ---------------------------------------------------------------------------
__device__ inline void ln_core(const float* __restrict__ Xp, const float* __restrict__ cb,
                               int s, int lane, float v[8], float* rs_out) {
  float x1[8], x2[8], x3[8], bi[8];
  load8(Xp + (size_t)s * D, lane, v);
  load8(Xp + (size_t)S * D + (size_t)s * D, lane, x1);
  load8(Xp + 2 * (size_t)S * D + (size_t)s * D, lane, x2);
  load8(Xp + 3 * (size_t)S * D + (size_t)s * D, lane, x3);
  load8(cb, lane, bi);
#pragma unroll
  for (int i = 0; i < 8; ++i) v[i] = ((v[i] + x1[i]) + (x2[i] + x3[i])) + bi[i];
  float sum = 0.f;
#pragma unroll
  for (int i = 0; i < 8; ++i) sum += v[i];
#pragma unroll
  for (int off = 32; off > 0; off >>= 1) sum += __shfl_xor(sum, off);
  const float m = sum * (1.0f / D);
  float sq = 0.f;
#pragma unroll
  for (int i = 0; i < 8; ++i) { v[i] -= m; sq += v[i] * v[i]; }
#pragma unroll
  for (int off = 32; off > 0; off >>= 1) sq += __shfl_xor(sq, off);
  *rs_out = rsqrtf(sq * (1.0f / D) + EPSLN);
}

// ---------------------------------------------------------------------------
// THE mega kernel: pack | gemm1 | LN1 | gemm2 | LN2+pred | scan | gather,
// separated by software grid barriers. 512 blocks x 256 threads.
// ---------------------------------------------------------------------------
__global__ __launch_bounds__(256, 2) void mega_kernel(
    const float* __restrict__ enc, const float* __restrict__ w1,
    const float* __restrict__ w2, const float* __restrict__ cb1,
    const float* __restrict__ g1, const float* __restrict__ be1,
    const float* __restrict__ cb2, const float* __restrict__ g2,
    const float* __restrict__ be2, const float* __restrict__ lw,
    const float* __restrict__ lb,
    ushort* __restrict__ Xph, ushort* __restrict__ Xpl,
    ushort* __restrict__ T1h, ushort* __restrict__ T1l,
    ushort* __restrict__ B1h, ushort* __restrict__ B1l,
    ushort* __restrict__ B2h, ushort* __restrict__ B2l,
    float* __restrict__ t0, int* __restrict__ dur, int* __restrict__ cum,
    int* __restrict__ bar, float* __restrict__ out0, float* __restrict__ out1) {
  __shared__ __align__(16) ushort smem[2][4][4096];   // 64 KB (GEMM phases)

  const int bid  = blockIdx.x;
  const int tid  = threadIdx.x;
  const int wave = tid >> 6;
  const int lane = tid & 63;

  // ---- Phase 0: pack everything -------------------------------------------
  for (int t = bid * 256 + tid; t < SP * 64; t += NBLK * 256) {
    const int g  = t >> 6;
    const int i0 = (t & 63) * 8;
    float vv[8] = {};
    if (g > 0 && g < SP - 1) {
      const float4 v0 = *(const float4*)(enc + (size_t)(g - 1) * D + i0);
      const float4 v1 = *(const float4*)(enc + (size_t)(g - 1) * D + i0 + 4);
      vv[0] = v0.x; vv[1] = v0.y; vv[2] = v0.z; vv[3] = v0.w;
      vv[4] = v1.x; vv[5] = v1.y; vv[6] = v1.z; vv[7] = v1.w;
    }
    short8 h8, l8;
#pragma unroll
    for (int j = 0; j < 8; ++j) {
      const ushort hi = f2bf(vv[j]);
      h8[j] = (short)hi;
      l8[j] = (short)f2bf(vv[j] - bf2f(hi));
    }
    const size_t dst = ((size_t)(i0 >> 5) * SP + g) * 32 + (i0 & 31);
    *(short8*)(Xph + dst) = h8;
    *(short8*)(Xpl + dst) = l8;
  }
  for (int q = bid * 256 + tid; q < NKT * D * 4; q += NBLK * 256)
    wpack8(w1, B1h, B1l, q);
  for (int q = bid * 256 + tid; q < NKT * D * 4; q += NBLK * 256)
    wpack8(w2, B2h, B2l, q);
  if (bid == 0) {
    for (int idx = tid; idx < NIT * 2 * 32; idx += 256) {
      const int c   = idx >> 6;
      const int rr  = (idx >> 5) & 1;
      const int col = idx & 31;
      const size_t off = ((size_t)c * SP + (rr ? (SP - 1) : 0)) * 32 + col;
      T1h[off] = 0;
      T1l[off] = 0;
    }
  }
  gridbar(bar, 0);

  // ---- Phase 1: GEMM 1 ----------------------------------------------------
  gemm_phase(Xph, Xpl, B1h, B1l, t0, smem, bid, tid);
  gridbar(bar, 1);

  // ---- Phase 2: LN1 + ReLU + pack (8 rows/block, 2 per wave) --------------
#pragma unroll
  for (int r2 = 0; r2 < 2; ++r2) {
    const int s = bid * 8 + wave * 2 + r2;
    float v[8], rs;
    ln_core(t0, cb1, s, lane, v, &rs);
    float gg[8], bt[8];
    load8(g1, lane, gg);
    load8(be1, lane, bt);
    short8 h8, l8;
#pragma unroll
    for (int i = 0; i < 8; ++i) {
      const float y = fmaxf(v[i] * rs * gg[i] + bt[i], 0.0f);
      const ushort hi = f2bf(y);
      h8[i] = (short)hi;
      l8[i] = (short)f2bf(y - bf2f(hi));
    }
    const size_t base = ((size_t)(lane >> 2) * SP + (s + 1)) * 32 + (size_t)(lane & 3) * 8;
    *(short8*)(T1h + base) = h8;
    *(short8*)(T1l + base) = l8;
  }
  gridbar(bar, 2);

  // ---- Phase 3: GEMM 2 ----------------------------------------------------
  gemm_phase(T1h, T1l, B2h, B2l, t0, smem, bid, tid);
  gridbar(bar, 3);

  // ---- Phase 4: LN2 + linear + floor(p+0.5) -------------------------------
#pragma unroll
  for (int r2 = 0; r2 < 2; ++r2) {
    const int s = bid * 8 + wave * 2 + r2;
    float v[8], rs;
    ln_core(t0, cb2, s, lane, v, &rs);
    float gg[8], bt[8], ww[8];
    load8(g2, lane, gg);
    load8(be2, lane, bt);
    load8(lw, lane, ww);
    float d = 0.f;
#pragma unroll
    for (int i = 0; i < 8; ++i) {
      const float y = fmaxf(v[i] * rs * gg[i] + bt[i], 0.0f);
      d += y * ww[i];
    }
#pragma unroll
    for (int off = 32; off > 0; off >>= 1) d += __shfl_xor(d, off);
    if (lane == 0) {
      const float p = fmaxf(d + lb[0], 0.0f);
      dur[s] = (int)floorf(p + 0.5f);
    }
  }
  gridbar(bar, 4);

  // ---- Phase 5: scan (block 0, wave 0 only) -------------------------------
  if (bid == 0 && tid < 64) {
    const int4* src = (const int4*)dur + (size_t)lane * 16;
    int4 vv[16];
    int run = 0;
#pragma unroll
    for (int i = 0; i < 16; ++i) {
      int4 d = src[i];
      d.x += run; d.y += d.x; d.z += d.y; d.w += d.z;
      run = d.w;
      vv[i] = d;
    }
    int sc = run;
#pragma unroll
    for (int off = 1; off < 64; off <<= 1) {
      const int n = __shfl_up(sc, off);
      if (lane >= off) sc += n;
    }
    const int base = sc - run;
    int4* dst = (int4*)cum + (size_t)lane * 16;
#pragma unroll
    for (int i = 0; i < 16; ++i) {
      int4 d = vv[i];
      d.x += base; d.y += base; d.z += base; d.w += base;
      dst[i] = d;
    }
  }
  gridbar(bar, 5);

  // ---- Phase 6: gather (32 frames/block) ----------------------------------
  const int total = cum[S - 1];
  const int hf = tid >> 7;                    // 0/1
  const int d4 = (tid & 127) << 2;            // 0..508
#pragma unroll 4
  for (int pass = 0; pass < 16; ++pass) {
    const int t = bid * 32 + pass * 2 + hf;
    int lo = 0, hi = S;
    while (lo < hi) {
      const int mid = (lo + hi) >> 1;
      if (cum[mid] <= t) lo = mid + 1; else hi = mid;
    }
    const int idx = (lo < S) ? lo : (S - 1);
    float4 v = make_float4(0.f, 0.f, 0.f, 0.f);
    if (t < total) v = *(const float4*)(enc + (size_t)idx * D + d4);
    *(float4*)(out0 + (size_t)t * D + d4) = v;
    if ((tid & 127) == 0) out1[t] = (float)(t + 1);
  }
}

// ---------------------------------------------------------------------------
extern "C" void kernel_launch(void* const* d_in, const int* in_sizes, int n_in,
                              void* d_out, int out_size, void* d_ws, size_t ws_size,
                              hipStream_t stream) {
  const float* enc = (const float*)d_in[0];
  const float* w1  = (const float*)d_in[1];
  const float* cb1 = (const float*)d_in[2];
  const float* g1  = (const float*)d_in[3];
  const float* be1 = (const float*)d_in[4];
  const float* w2  = (const float*)d_in[5];
  const float* cb2 = (const float*)d_in[6];
  const float* g2  = (const float*)d_in[7];
  const float* be2 = (const float*)d_in[8];
  const float* lw  = (const float*)d_in[9];
  const float* lb  = (const float*)d_in[10];

  float* out0 = (float*)d_out;                 // [MAXOUT, D]
  float* out1 = out0 + (size_t)MAXOUT * D;     // [MAXOUT]

  const size_t NP = (size_t)NIT * SP * 32;     // packed activation elems
  const size_t NB = (size_t)NKT * D * 32;      // packed weight elems
  ushort* Xph = (ushort*)d_ws;
  ushort* Xpl = Xph + NP;
  ushort* T1h = Xpl + NP;
  ushort* T1l = T1h + NP;
  ushort* B1h = T1l + NP;
  ushort* B1l = B1h + NB;
  ushort* B2h = B1l + NB;
  ushort* B2l = B2h + NB;
  float*  t0  = (float*)(B2l + NB);            // KSPLIT x S*D fp32 partials
  int*   dur  = (int*)(t0 + (size_t)KSPLIT * S * D);
  int*   cum  = dur + S;
  int*   bar  = cum + S;                       // 16 ints, zeroed per launch

  zero_bar_kernel<<<1, 64, 0, stream>>>(bar);
  mega_kernel<<<NBLK, 256, 0, stream>>>(
      enc, w1, w2, cb1, g1, be1, cb2, g2, be2, lw, lb,
      Xph, Xpl, T1h, T1l, B1h, B1l, B2h, B2l, t0, dur, cum, bar, out0, out1);
}